// Round 15
// baseline (291.450 us; speedup 1.0000x reference)
//
#include <hip/hip_runtime.h>
#include <stdint.h>

#define NQ   8192
#define NB   2
#define KNN  10
#define K1   11                 // top-11 incl. self (dist 0 = global min key); dropped at end
#define NTOT (NB * NQ)
#define IDXMASK 0x1FFFu
#define PAD  2e-3f              // dpr-vs-exact-key slack (fp err <= ~4e-4)

// tau: per query, 11th-smallest dpr over a fixed 1024-point subsample (stride 8)
#define SUBS    1024
#define SSTRIDE 8
#define TW      16              // waves per tau block (1024 thr, 64 queries)
#define CKI(s, c, lane) (((s) * TW + (c)) * 64 + (lane))

// scan: group of 256 queries x 8 blocks; each block scans 1024 candidates, 4 q/lane
#define HB    8
#define CPB   (NQ / HB)         // 1024
#define QPB   256               // queries per scan block
#define WPS   16                // waves per scan block (1024 threads)
#define CPWT  (CPB / WPS)       // 64 broadcasts per wave (x4 queries)
#define CAPQ  32                // per (query, block); lambda ~11
#define LSTR  33

static __device__ __forceinline__ uint32_t umin32(uint32_t a, uint32_t b) { return a < b ? a : b; }
static __device__ __forceinline__ uint32_t umax32(uint32_t a, uint32_t b) { return a > b ? a : b; }

static __device__ __forceinline__ void insert11(uint32_t (&l)[K1], uint32_t key) {
#pragma unroll
    for (int s = 0; s < K1; ++s) {
        const uint32_t m = l[s];
        l[s] = umin32(key, m);
        key  = umax32(key, m);
    }
}
static __device__ __forceinline__ void insert11f(float (&l)[K1], float v) {
#pragma unroll
    for (int s = 0; s < K1; ++s) {
        const float m = l[s];
        l[s] = fminf(v, m);
        v    = fmaxf(v, m);
    }
}

// ---------------- kernel 1: per-query tau (dpr space); zeroes loss accumulator ----------------
__global__ __launch_bounds__(1024, 4) void plap_tau(
    const float* __restrict__ p1, float* __restrict__ tauDpr, float* __restrict__ out)
{
    __shared__ float2 sxy[SUBS];                       // 8 KB (x,y)
    __shared__ float2 szc[SUBS];                       // 8 KB (z,|c|^2)
    __shared__ float  ck[K1 * TW * 64];                // 45056 B

    const int tid  = threadIdx.x;
    const int lane = tid & 63;
    const int wave = tid >> 6;
    const int wq   = __builtin_amdgcn_readfirstlane(wave);
    const int b    = blockIdx.x >> 7;
    const int qi   = ((blockIdx.x & 127) << 6) | lane;
    const float* __restrict__ P = p1 + (size_t)b * NQ * 3;

    if (blockIdx.x == 0 && tid == 0) out[0] = 0.0f;    // replaces memset dispatch
    {
        const float* src = P + (size_t)(tid * SSTRIDE) * 3;  // 1024 samples, 1/thread
        const float x = src[0], y = src[1], z = src[2];
        sxy[tid] = make_float2(x, y);
        szc[tid] = make_float2(z, fmaf(x, x, fmaf(y, y, z * z)));
    }
    const float qx = P[qi * 3 + 0];
    const float qy = P[qi * 3 + 1];
    const float qz = P[qi * 3 + 2];
    __syncthreads();

    float l[K1];
#pragma unroll
    for (int s = 0; s < K1; ++s) l[s] = __builtin_inff();
    const int t0 = wq * (SUBS / TW);                   // 64 samples per wave
#pragma unroll 4
    for (int t = t0; t < t0 + SUBS / TW; ++t) {
        const float2 a  = sxy[t];
        const float2 zc = szc[t];
        const float s3  = fmaf(qx, a.x, fmaf(qy, a.y, qz * zc.x));
        insert11f(l, fmaf(-2.0f, s3, zc.y));           // dpr = |c|^2 - 2 q.c
    }
#pragma unroll
    for (int s = 0; s < K1; ++s) ck[CKI(s, wq, lane)] = l[s];
    __syncthreads();

    for (int st = 1; st < TW; st <<= 1) {              // tree-merge -> 11th of 1024
        if ((wq & (2 * st - 1)) == 0) {
            float A[K1];
#pragma unroll
            for (int s = 0; s < K1; ++s) A[s] = ck[CKI(s, wq, lane)];
#pragma unroll
            for (int e = 0; e < K1; ++e) insert11f(A, ck[CKI(e, wq + st, lane)]);
            if (2 * st < TW) {
#pragma unroll
                for (int s = 0; s < K1; ++s) ck[CKI(s, wq, lane)] = A[s];
            } else {
                tauDpr[blockIdx.x * 64 + lane] = A[K1 - 1];
            }
        }
        __syncthreads();
    }
}

// ---------------- kernel 2: filtered scan, 4 queries/lane, dot-form filter ----------------
__global__ __launch_bounds__(1024, 8) void plap_scan(
    const float* __restrict__ p1, const float* __restrict__ tauDpr,
    uint32_t* __restrict__ keysG, uint32_t* __restrict__ cntG)
{
    __shared__ float2 sxy[CPB];                        // 8 KB
    __shared__ float2 szc[CPB];                        // 8 KB
    __shared__ uint32_t lists[QPB * LSTR];             // 33792 B
    __shared__ uint32_t cnt[QPB];                      // 1 KB  -> ~51 KB (2 blocks/CU by grid)

    const int tid   = threadIdx.x;
    const int lane  = tid & 63;
    const int wave  = tid >> 6;
    const int wq    = __builtin_amdgcn_readfirstlane(wave);
    const int group = blockIdx.x >> 3;                 // 0..63 (256-query groups)
    const int hb    = blockIdx.x & 7;
    const int b     = group >> 5;                      // 32 groups per batch
    const int qb    = (group & 31) << 8;               // query base within batch
    const float* __restrict__ P = p1 + (size_t)b * NQ * 3;

    float qx[4], qy[4], qz[4], tc[4];
#pragma unroll
    for (int k = 0; k < 4; ++k) {
        const int qi = qb + k * 64 + lane;
        qx[k] = P[qi * 3 + 0];
        qy[k] = P[qi * 3 + 1];
        qz[k] = P[qi * 3 + 2];
        tc[k] = tauDpr[(size_t)group * 256 + k * 64 + lane] + PAD;
    }

    if (tid < QPB) cnt[tid] = 0;
    const int j0 = hb * CPB;
    {
        const float* src = P + (size_t)(j0 + tid) * 3; // 1024 candidates, 1/thread
        const float x = src[0], y = src[1], z = src[2];
        sxy[tid] = make_float2(x, y);
        szc[tid] = make_float2(z, fmaf(x, x, fmaf(y, y, z * z)));
    }
    __syncthreads();

    const int c0 = wq * CPWT;
#pragma unroll 8
    for (int t = 0; t < CPWT; ++t) {
        const int c = c0 + t;
        const float2 a  = sxy[c];                      // ds_read_b64 broadcast
        const float2 zc = szc[c];                      // ds_read_b64 broadcast
#pragma unroll
        for (int k = 0; k < 4; ++k) {
            const float s3  = fmaf(qx[k], a.x, fmaf(qy[k], a.y, qz[k] * zc.x));
            const float dpr = fmaf(-2.0f, s3, zc.y);
            if (dpr <= tc[k]) {
                const float dx = qx[k] - a.x, dy = qy[k] - a.y, dz = qz[k] - zc.x;
                const float d  = fmaf(dx, dx, fmaf(dy, dy, dz * dz));  // exact key formula
                const uint32_t key = (__float_as_uint(d) & ~IDXMASK) | (uint32_t)(j0 + c);
                const int ql = k * 64 + lane;
                const uint32_t old = atomicAdd(&cnt[ql], 1u);
                if (old < CAPQ) lists[ql * LSTR + old] = key;
            }
        }
    }
    __syncthreads();

    // write-out: counts + keys, query-contiguous layout [qid][hb][slot]
    if (tid < QPB) cntG[(size_t)(group * 256 + tid) * HB + hb] = cnt[tid];
    {
        const int ql = tid & (QPB - 1);                // query-local 0..255
        const int s0 = tid >> 8;                       // 4 writer threads per query
        const uint32_t cc = umin32(cnt[ql], CAPQ);
        uint32_t* __restrict__ dst =
            keysG + (size_t)(group * 256 + ql) * (HB * CAPQ) + (size_t)hb * CAPQ;
        for (uint32_t s = s0; s < cc; s += 4) dst[s] = lists[ql * LSTR + s];
    }
}

// ---------------- kernel 3: parallel merge (4 waves x 2 lists) + loss ----------------
__global__ __launch_bounds__(256) void plap_merge_loss(
    const float* __restrict__ p1, const float* __restrict__ p2,
    const uint32_t* __restrict__ keysG, const uint32_t* __restrict__ cntG,
    float* __restrict__ out)
{
    __shared__ uint32_t sk[4 * K1 * 64];               // 11264 B, lane-major
    const int ql = threadIdx.x & 63;
    const int w  = threadIdx.x >> 6;                   // 0..3
    const int wu = __builtin_amdgcn_readfirstlane(w);
    const int qid = blockIdx.x * 64 + ql;              // 0..NTOT-1
    const int b   = qid >> 13;
    const int qi  = qid & (NQ - 1);
    const float* __restrict__ P1 = p1 + (size_t)b * NQ * 3;
    const float* __restrict__ P2 = p2 + (size_t)b * NQ * 3;

    const float qx = P1[qi * 3 + 0];
    const float qy = P1[qi * 3 + 1];
    const float qz = P1[qi * 3 + 2];

    uint32_t F[K1];
#pragma unroll
    for (int s = 0; s < K1; ++s) F[s] = 0xFFFFFFFFu;

#pragma unroll
    for (int hh = 0; hh < 2; ++hh) {
        const int h = 2 * wu + hh;
        const uint32_t c = cntG[(size_t)qid * HB + h];
        if (c <= CAPQ) {
            const uint32_t* __restrict__ src =
                keysG + (size_t)qid * (HB * CAPQ) + (size_t)h * CAPQ;
            for (uint32_t s = 0; s < c; ++s) insert11(F, src[s]);
        } else {
            // exact fallback (rare): rescan this eighth
            for (int j = h * CPB; j < (h + 1) * CPB; ++j) {
                const float dx = qx - P1[j * 3 + 0];
                const float dy = qy - P1[j * 3 + 1];
                const float dz = qz - P1[j * 3 + 2];
                const float d  = fmaf(dx, dx, fmaf(dy, dy, dz * dz));
                insert11(F, (__float_as_uint(d) & ~IDXMASK) | (uint32_t)j);
            }
        }
    }

#pragma unroll
    for (int s = 0; s < K1; ++s) sk[(wu * K1 + s) * 64 + ql] = F[s];
    for (int st = 1; st < 4; st <<= 1) {
        __syncthreads();
        if ((wu & (2 * st - 1)) == 0) {
#pragma unroll
            for (int e = 0; e < K1; ++e) insert11(F, sk[((wu + st) * K1 + e) * 64 + ql]);
            if (2 * st < 4) {
#pragma unroll
                for (int s = 0; s < K1; ++s) sk[(wu * K1 + s) * 64 + ql] = F[s];
            }
        }
    }

    if (wu == 0) {
        float s1x = 0.f, s1y = 0.f, s1z = 0.f, s2x = 0.f, s2y = 0.f, s2z = 0.f;
#pragma unroll
        for (int s = 1; s < K1; ++s) {                 // F[0] = self (d = 0)
            const int n = (int)(F[s] & IDXMASK);
            s1x += P1[n * 3 + 0]; s1y += P1[n * 3 + 1]; s1z += P1[n * 3 + 2];
            s2x += P2[n * 3 + 0]; s2y += P2[n * 3 + 1]; s2z += P2[n * 3 + 2];
        }
        const float invk = 1.0f / (float)KNN;
        const float lx = (s1x * invk - qx) - (s2x * invk - P2[qi * 3 + 0]);
        const float ly = (s1y * invk - qy) - (s2y * invk - P2[qi * 3 + 1]);
        const float lz = (s1z * invk - qz) - (s2z * invk - P2[qi * 3 + 2]);
        float acc = fabsf(lx) + fabsf(ly) + fabsf(lz);
#pragma unroll
        for (int off = 32; off > 0; off >>= 1)
            acc += __shfl_down(acc, off, 64);
        if (ql == 0) atomicAdd(out, acc * (1.0f / (float)(NTOT * 3)));
    }
}

extern "C" void kernel_launch(void* const* d_in, const int* in_sizes, int n_in,
                              void* d_out, int out_size, void* d_ws, size_t ws_size,
                              hipStream_t stream) {
    const float* p1 = (const float*)d_in[0];
    const float* p2 = (const float*)d_in[1];
    float* out      = (float*)d_out;

    // ws: tauDpr 64 KB | cnt 512 KB | keys (NTOT*HB*CAPQ*4 = 16.8 MB)
    float*    tauD  = (float*)d_ws;
    uint32_t* cntG  = (uint32_t*)(tauD + NTOT);
    uint32_t* keysG = cntG + (size_t)NTOT * HB;

    plap_tau <<<dim3(NTOT / 64), dim3(TW * 64), 0, stream>>>(p1, tauD, out);
    plap_scan<<<dim3(NTOT / QPB * HB), dim3(1024), 0, stream>>>(p1, tauD, keysG, cntG);
    plap_merge_loss<<<dim3(NTOT / 64), dim3(256), 0, stream>>>(p1, p2, keysG, cntG, out);
}